// Round 1
// baseline (110.334 us; speedup 1.0000x reference)
//
#include <hip/hip_runtime.h>

#define BATCH 64
#define N_IN  2048
#define NN    512
#define NCH   64          // n columns per block
#define ALPHA 0.995f
#define BETA  0.975f
#define V_TH  2.0f

__global__ __launch_bounds__(256)
void fused_step(const float* __restrict__ x,
                const float* __restrict__ v,
                const float* __restrict__ z,
                const float* __restrict__ z_out,
                const float* __restrict__ w,
                float* __restrict__ out)
{
    const int b   = blockIdx.y;
    const int nb  = blockIdx.x * NCH;
    const int tid = threadIdx.x;
    const int nl  = tid & 15;   // float4 column within the 64-wide n chunk
    const int kk  = tid >> 4;   // k-row group 0..15

    __shared__ float  zlds[NN];     // z_out_new for this batch (all 512 neurons)
    __shared__ float4 red[256];     // drive1 reduction
    __shared__ float  red2[256];    // drive2 reduction

    // ---- z_out_new = BETA * z_out + z  (needed in full for the LOO gather)
    for (int i = tid; i < NN; i += 256) {
        zlds[i] = BETA * z_out[b * NN + i] + z[b * NN + i];
    }

    // ---- drive1 = sum_k x[b,k,n] * w[k,n]   (the 268 MB stream)
    const float4* __restrict__ x4 = (const float4*)(x + (size_t)b * N_IN * NN + nb);
    const float4* __restrict__ w4 = (const float4*)(w + nb);
    float4 acc = make_float4(0.f, 0.f, 0.f, 0.f);
#pragma unroll 8
    for (int k = kk; k < N_IN; k += 16) {
        const float4 xv = x4[(size_t)k * (NN / 4) + nl];
        const float4 wv = w4[(size_t)k * (NN / 4) + nl];
        acc.x += xv.x * wv.x;
        acc.y += xv.y * wv.y;
        acc.z += xv.z * wv.z;
        acc.w += xv.w * wv.w;
    }
    red[tid] = acc;
    __syncthreads();            // also covers zlds writes
#pragma unroll
    for (int s = 128; s >= 16; s >>= 1) {
        if (tid < s) {
            const float4 o = red[tid + s];
            red[tid].x += o.x; red[tid].y += o.y;
            red[tid].z += o.z; red[tid].w += o.w;
        }
        __syncthreads();
    }
    // floats 0..63 of red now hold drive1 for n = nb .. nb+63

    // ---- drive2 = sum_j z_out_new[b, j + (j>=n)] * w[N_IN + j, n]
    const int n_loc = tid & 63;
    const int n     = nb + n_loc;
    const int jg    = tid >> 6;          // 0..3 j-interleave groups
    float d2 = 0.f;
    for (int j = jg; j < NN - 1; j += 4) {
        d2 += zlds[j + (j >= n)] * w[(size_t)(N_IN + j) * NN + n];
    }
    red2[tid] = d2;
    __syncthreads();

    // ---- epilogue: v_new, z_new, z_out_new
    if (tid < 64) {
        const float d1  = ((const float*)red)[n_loc];
        const float d2s = red2[n_loc] + red2[n_loc + 64]
                        + red2[n_loc + 128] + red2[n_loc + 192];
        const float vv = v[b * NN + n];
        const float zz = z[b * NN + n];
        const float v_new = ALPHA * vv + d1 + d2s - V_TH * zz;
        out[b * NN + n]                  = v_new;
        out[BATCH * NN + b * NN + n]     = (v_new - V_TH > 0.f) ? 1.f : 0.f;
        out[2 * BATCH * NN + b * NN + n] = zlds[n];
    }
}

extern "C" void kernel_launch(void* const* d_in, const int* in_sizes, int n_in,
                              void* d_out, int out_size, void* d_ws, size_t ws_size,
                              hipStream_t stream) {
    (void)in_sizes; (void)n_in; (void)out_size; (void)d_ws; (void)ws_size;
    const float* x     = (const float*)d_in[0];
    const float* v     = (const float*)d_in[1];
    const float* z     = (const float*)d_in[2];
    const float* z_out = (const float*)d_in[3];
    const float* w     = (const float*)d_in[4];
    float* out = (float*)d_out;

    dim3 grid(NN / NCH, BATCH);   // 8 x 64 = 512 blocks
    fused_step<<<grid, 256, 0, stream>>>(x, v, z, z_out, w, out);
}

// Round 2
// 62.121 us; speedup vs baseline: 1.7761x; 1.7761x over previous
//
#include <hip/hip_runtime.h>

#define BATCH 64
#define N_IN  2048
#define NN    512
#define NCH   64          // n columns per block
#define THREADS 1024
#define ALPHA 0.995f
#define BETA  0.975f
#define V_TH  2.0f

__global__ __launch_bounds__(THREADS)
void fused_step(const float* __restrict__ x,
                const float* __restrict__ v,
                const float* __restrict__ z,
                const float* __restrict__ z_out,
                const float* __restrict__ w,
                float* __restrict__ out)
{
    const int b   = blockIdx.y;
    const int nb  = blockIdx.x * NCH;
    const int tid = threadIdx.x;
    const int nl  = tid & 15;   // float4 column within the 64-wide n chunk
    const int kk  = tid >> 4;   // k-row group 0..63

    __shared__ float  zlds[NN];       // z_out_new for this batch (2 KB)
    __shared__ float4 red[THREADS];   // drive1 reduction (16 KB)
    __shared__ float  red2[THREADS];  // drive2 reduction (4 KB)

    // ---- z_out_new = BETA * z_out + z  (needed in full for the LOO gather)
    for (int i = tid; i < NN; i += THREADS) {
        zlds[i] = BETA * z_out[b * NN + i] + z[b * NN + i];
    }

    // ---- drive1 = sum_k x[b,k,n] * w[k,n]   (the 268 MB stream)
    const float4* __restrict__ x4 = (const float4*)(x + (size_t)b * N_IN * NN + nb);
    const float4* __restrict__ w4 = (const float4*)(w + nb);
    float4 acc = make_float4(0.f, 0.f, 0.f, 0.f);
#pragma unroll 8
    for (int k = kk; k < N_IN; k += 64) {   // 32 iterations
        const float4 xv = x4[(size_t)k * (NN / 4) + nl];
        const float4 wv = w4[(size_t)k * (NN / 4) + nl];
        acc.x += xv.x * wv.x;
        acc.y += xv.y * wv.y;
        acc.z += xv.z * wv.z;
        acc.w += xv.w * wv.w;
    }
    red[tid] = acc;
    __syncthreads();            // also covers zlds writes
#pragma unroll
    for (int s = 512; s >= 16; s >>= 1) {
        if (tid < s) {
            const float4 o = red[tid + s];
            red[tid].x += o.x; red[tid].y += o.y;
            red[tid].z += o.z; red[tid].w += o.w;
        }
        __syncthreads();
    }
    // floats 0..63 of red now hold drive1 for n = nb .. nb+63

    // ---- drive2 = sum_j z_out_new[b, j + (j>=n)] * w[N_IN + j, n]
    const int n_loc = tid & 63;
    const int n     = nb + n_loc;
    const int jg    = tid >> 6;          // 0..15 j-interleave groups
    float d2 = 0.f;
    for (int j = jg; j < NN - 1; j += 16) {   // ~32 iterations
        d2 += zlds[j + (j >= n)] * w[(size_t)(N_IN + j) * NN + n];
    }
    red2[tid] = d2;
    __syncthreads();

    // ---- epilogue: v_new, z_new, z_out_new
    if (tid < 64) {
        const float d1 = ((const float*)red)[n_loc];
        float d2s = 0.f;
#pragma unroll
        for (int g = 0; g < 16; ++g) d2s += red2[n_loc + 64 * g];
        const float vv = v[b * NN + n];
        const float zz = z[b * NN + n];
        const float v_new = ALPHA * vv + d1 + d2s - V_TH * zz;
        out[b * NN + n]                  = v_new;
        out[BATCH * NN + b * NN + n]     = (v_new - V_TH > 0.f) ? 1.f : 0.f;
        out[2 * BATCH * NN + b * NN + n] = zlds[n];
    }
}

extern "C" void kernel_launch(void* const* d_in, const int* in_sizes, int n_in,
                              void* d_out, int out_size, void* d_ws, size_t ws_size,
                              hipStream_t stream) {
    (void)in_sizes; (void)n_in; (void)out_size; (void)d_ws; (void)ws_size;
    const float* x     = (const float*)d_in[0];
    const float* v     = (const float*)d_in[1];
    const float* z     = (const float*)d_in[2];
    const float* z_out = (const float*)d_in[3];
    const float* w     = (const float*)d_in[4];
    float* out = (float*)d_out;

    dim3 grid(NN / NCH, BATCH);   // 8 x 64 = 512 blocks, 2 per CU, 32 waves/CU
    fused_step<<<grid, THREADS, 0, stream>>>(x, v, z, z_out, w, out);
}

// Round 3
// 57.828 us; speedup vs baseline: 1.9080x; 1.0742x over previous
//
#include <hip/hip_runtime.h>

#define BATCH 64
#define N_IN  2048
#define NN    512
#define NCH   64          // n columns per block
#define THREADS 1024
#define ALPHA 0.995f
#define BETA  0.975f
#define V_TH  2.0f

__global__ __launch_bounds__(THREADS, 8)   // cap VGPR<=64: keep 2 blocks/CU, 32 waves/CU
void fused_step(const float* __restrict__ x,
                const float* __restrict__ v,
                const float* __restrict__ z,
                const float* __restrict__ z_out,
                const float* __restrict__ w,
                float* __restrict__ out)
{
    const int b    = blockIdx.y;
    const int nb   = blockIdx.x * NCH;
    const int tid  = threadIdx.x;
    const int nl   = tid & 15;   // float4 column within the 64-wide n chunk
    const int kk   = tid >> 4;   // k-row group 0..63
    const int wid  = tid >> 6;   // wave 0..15
    const int lane = tid & 63;

    __shared__ float  zlds[NN];        // z_out_new for this batch (2 KB)
    __shared__ float4 wpart[16][16];   // per-wave drive1 partials [wave][nl] (4 KB)
    __shared__ float4 d1s[16];         // final drive1 (256 B)
    __shared__ float  red2[THREADS];   // drive2 partials (4 KB)

    // ---- z_out_new = BETA * z_out + z  (full row needed for the LOO gather)
    for (int i = tid; i < NN; i += THREADS)
        zlds[i] = BETA * z_out[b * NN + i] + z[b * NN + i];

    // ---- drive1 = sum_k x[b,k,n] * w[k,n]  -- explicit 8-load batches for MLP
    const float4* __restrict__ x4 = (const float4*)(x + (size_t)b * N_IN * NN + nb);
    const float4* __restrict__ w4 = (const float4*)(w + nb);
    const float4* xp = x4 + (size_t)kk * (NN / 4) + nl;
    const float4* wp = w4 + (size_t)kk * (NN / 4) + nl;
    const size_t kstride = (size_t)64 * (NN / 4);   // 64 k-rows per step

    float4 acc = make_float4(0.f, 0.f, 0.f, 0.f);
#pragma unroll 2
    for (int i = 0; i < 8; ++i) {
        float4 xv[4], wvv[4];
#pragma unroll
        for (int u = 0; u < 4; ++u) xv[u]  = xp[u * kstride];   // HBM stream first
#pragma unroll
        for (int u = 0; u < 4; ++u) wvv[u] = wp[u * kstride];   // L2-hot second
#pragma unroll
        for (int u = 0; u < 4; ++u) {
            acc.x += xv[u].x * wvv[u].x;
            acc.y += xv[u].y * wvv[u].y;
            acc.z += xv[u].z * wvv[u].z;
            acc.w += xv[u].w * wvv[u].w;
        }
        xp += 4 * kstride;
        wp += 4 * kstride;
    }

    // ---- in-wave reduce over the 4 k-groups (lanes l, l+16, l+32, l+48)
#pragma unroll
    for (int off = 32; off >= 16; off >>= 1) {
        acc.x += __shfl_down(acc.x, off);
        acc.y += __shfl_down(acc.y, off);
        acc.z += __shfl_down(acc.z, off);
        acc.w += __shfl_down(acc.w, off);
    }
    if (lane < 16) wpart[wid][lane] = acc;
    __syncthreads();   // covers zlds + wpart

    // ---- drive2 = sum_j z_out_new[b, j+(j>=n)] * w[N_IN+j, n]  (all threads)
    const int n_loc = tid & 63;
    const int n     = nb + n_loc;
    const int jg    = tid >> 6;          // 16 j-interleave groups
    float d2 = 0.f;
    for (int j = jg; j < NN - 1; j += 16)
        d2 += zlds[j + (j >= n)] * w[(size_t)(N_IN + j) * NN + n];
    red2[tid] = d2;

    // ---- drive1 column sums (threads 0..15, concurrent with other waves' drive2)
    if (tid < 16) {
        float4 s = wpart[0][tid];
#pragma unroll
        for (int ww = 1; ww < 16; ++ww) {
            const float4 o = wpart[ww][tid];
            s.x += o.x; s.y += o.y; s.z += o.z; s.w += o.w;
        }
        d1s[tid] = s;
    }
    __syncthreads();

    // ---- epilogue
    if (tid < 64) {
        const float d1 = ((const float*)d1s)[n_loc];
        float d2s = 0.f;
#pragma unroll
        for (int g = 0; g < 16; ++g) d2s += red2[n_loc + 64 * g];
        const float vv = v[b * NN + n];
        const float zz = z[b * NN + n];
        const float v_new = ALPHA * vv + d1 + d2s - V_TH * zz;
        out[b * NN + n]                  = v_new;
        out[BATCH * NN + b * NN + n]     = (v_new - V_TH > 0.f) ? 1.f : 0.f;
        out[2 * BATCH * NN + b * NN + n] = zlds[n];
    }
}

extern "C" void kernel_launch(void* const* d_in, const int* in_sizes, int n_in,
                              void* d_out, int out_size, void* d_ws, size_t ws_size,
                              hipStream_t stream) {
    (void)in_sizes; (void)n_in; (void)out_size; (void)d_ws; (void)ws_size;
    const float* x     = (const float*)d_in[0];
    const float* v     = (const float*)d_in[1];
    const float* z     = (const float*)d_in[2];
    const float* z_out = (const float*)d_in[3];
    const float* w     = (const float*)d_in[4];
    float* out = (float*)d_out;

    dim3 grid(NN / NCH, BATCH);   // 8 x 64 = 512 blocks, 2/CU, 32 waves/CU
    fused_step<<<grid, THREADS, 0, stream>>>(x, v, z, z_out, w, out);
}